// Round 1
// baseline (262.065 us; speedup 1.0000x reference)
//
#include <hip/hip_runtime.h>
#include <hip/hip_bf16.h>

#define SEQ 4096
#define BATCH 2
#define DMODEL 1024
#define NH 16
#define HDIM 64
#define NEGF (-3.0e38f)

typedef __attribute__((ext_vector_type(8))) short bf16x8;
typedef __attribute__((ext_vector_type(8))) unsigned short us8;
typedef __attribute__((ext_vector_type(4))) unsigned short us4;
typedef __attribute__((ext_vector_type(4))) float f32x4;

__device__ __forceinline__ unsigned short f2bf(float f) {
    union { float f; unsigned u; } v; v.f = f;
    unsigned u = v.u;
    return (unsigned short)((u + 0x7fffu + ((u >> 16) & 1u)) >> 16);
}

// ---------------- weight transpose + bf16 convert ----------------
// Wt[n][k] = W[k][n] * scale   (so GEMM B-operand reads are k-contiguous)
__global__ __launch_bounds__(256) void transpose_w(const float* __restrict__ W,
                                                   unsigned short* __restrict__ Wt,
                                                   float scale) {
    __shared__ float tile[64][65];
    const int n0 = blockIdx.x * 64, k0 = blockIdx.y * 64;
    const int tx = threadIdx.x;       // 0..63
    for (int dy = threadIdx.y; dy < 64; dy += 4)
        tile[dy][tx] = W[(size_t)(k0 + dy) * DMODEL + n0 + tx];
    __syncthreads();
    for (int dy = threadIdx.y; dy < 64; dy += 4)
        Wt[(size_t)(n0 + dy) * DMODEL + k0 + tx] = f2bf(tile[tx][dy] * scale);
}

__global__ __launch_bounds__(256) void build_bcat(const float* __restrict__ bq,
                                                  const float* __restrict__ bk,
                                                  const float* __restrict__ bv,
                                                  float* __restrict__ bcat) {
    int i = blockIdx.x * 256 + threadIdx.x;  // 0..3071
    float v;
    if (i < 1024) v = bq[i] * 0.125f;
    else if (i < 2048) v = bk[i - 1024];
    else v = bv[i - 2048];
    bcat[i] = v;
}

// xb[b*SEQ+s][d] = bf16(query[s][b][d])
__global__ __launch_bounds__(256) void convert_x(const float* __restrict__ q,
                                                 unsigned short* __restrict__ xb) {
    int t = blockIdx.x * 256 + threadIdx.x;   // 2M threads, 4 elems each
    int d4 = (t & 255) * 4;
    int row = t >> 8;                          // b*SEQ + s
    int b = row >> 12, s = row & (SEQ - 1);
    float4 v = *(const float4*)(q + ((size_t)s * BATCH + b) * DMODEL + d4);
    us4 o;
    o[0] = f2bf(v.x); o[1] = f2bf(v.y); o[2] = f2bf(v.z); o[3] = f2bf(v.w);
    *(us4*)(xb + (size_t)row * DMODEL + d4) = o;
}

// ---------------- 128x128 MFMA GEMM, BK=32, 4 waves ----------------
// MODE 0: C = xb @ [Wq|Wk|Wv]  -> qb/kb (b,h,s,hd) bf16, vtb (b,h,hd,s) bf16
// MODE 1: C = ao @ Wo + bo     -> out fp32, stored (s,b,d)
template <int MODE>
__global__ __launch_bounds__(256) void gemm128(const unsigned short* __restrict__ A,
                                               const unsigned short* __restrict__ Bt,
                                               const float* __restrict__ bias,
                                               unsigned short* __restrict__ qb,
                                               unsigned short* __restrict__ kb,
                                               unsigned short* __restrict__ vtb,
                                               float* __restrict__ out) {
    __shared__ __align__(16) unsigned short As[128][40];
    __shared__ __align__(16) unsigned short Bs[128][40];
    const int tid = threadIdx.x;
    const int lane = tid & 63, wid = tid >> 6;
    const int lr = lane & 15, lg = lane >> 4;
    const int wr = wid >> 1, wc = wid & 1;
    const int m0 = blockIdx.y * 128, n0 = blockIdx.x * 128;
    const int arow = tid >> 1, ahalf = tid & 1;

    f32x4 acc[4][4];
#pragma unroll
    for (int m = 0; m < 4; ++m)
#pragma unroll
        for (int n = 0; n < 4; ++n) {
            f32x4 z = {0.f, 0.f, 0.f, 0.f};
            acc[m][n] = z;
        }

    for (int k0 = 0; k0 < DMODEL; k0 += 32) {
        __syncthreads();
        us8 a0 = *(const us8*)(A + (size_t)(m0 + arow) * DMODEL + k0 + ahalf * 16);
        us8 a1 = *(const us8*)(A + (size_t)(m0 + arow) * DMODEL + k0 + ahalf * 16 + 8);
        us8 b0 = *(const us8*)(Bt + (size_t)(n0 + arow) * DMODEL + k0 + ahalf * 16);
        us8 b1 = *(const us8*)(Bt + (size_t)(n0 + arow) * DMODEL + k0 + ahalf * 16 + 8);
        *(us8*)&As[arow][ahalf * 16] = a0;
        *(us8*)&As[arow][ahalf * 16 + 8] = a1;
        *(us8*)&Bs[arow][ahalf * 16] = b0;
        *(us8*)&Bs[arow][ahalf * 16 + 8] = b1;
        __syncthreads();
        bf16x8 af[4], bfr[4];
#pragma unroll
        for (int m = 0; m < 4; ++m)
            af[m] = *(const bf16x8*)&As[wr * 64 + m * 16 + lr][lg * 8];
#pragma unroll
        for (int n = 0; n < 4; ++n)
            bfr[n] = *(const bf16x8*)&Bs[wc * 64 + n * 16 + lr][lg * 8];
#pragma unroll
        for (int m = 0; m < 4; ++m)
#pragma unroll
            for (int n = 0; n < 4; ++n)
                acc[m][n] = __builtin_amdgcn_mfma_f32_16x16x32_bf16(af[m], bfr[n], acc[m][n], 0, 0, 0);
    }

#pragma unroll
    for (int n = 0; n < 4; ++n) {
        const int col = n0 + wc * 64 + n * 16 + lr;
        const float bval = bias[col];
#pragma unroll
        for (int m = 0; m < 4; ++m) {
            const int row0 = m0 + wr * 64 + m * 16 + lg * 4;
            if (MODE == 0) {
                const int proj = col >> 10;
                const int ch = col & 1023;
                const int h = ch >> 6, hd = ch & 63;
                if (proj == 2) {
                    const int b = row0 >> 12, s = row0 & (SEQ - 1);
                    us4 o;
#pragma unroll
                    for (int r = 0; r < 4; ++r) o[r] = f2bf(acc[m][n][r] + bval);
                    *(us4*)(vtb + ((size_t)(b * NH + h) * HDIM + hd) * SEQ + s) = o;
                } else {
                    unsigned short* dst = (proj == 0) ? qb : kb;
#pragma unroll
                    for (int r = 0; r < 4; ++r) {
                        const int row = row0 + r;
                        const int b = row >> 12, s = row & (SEQ - 1);
                        dst[((size_t)(b * NH + h) * SEQ + s) * HDIM + hd] = f2bf(acc[m][n][r] + bval);
                    }
                }
            } else {
#pragma unroll
                for (int r = 0; r < 4; ++r) {
                    const int row = row0 + r;
                    const int b = row >> 12, s = row & (SEQ - 1);
                    out[((size_t)s * BATCH + b) * DMODEL + col] = acc[m][n][r] + bval;
                }
            }
        }
    }
}

// ---------------- banded flash attention ----------------
// block = 4 waves, 64 query rows; wave owns 16 rows. 32-key tiles.
__global__ __launch_bounds__(256) void attn_kernel(const unsigned short* __restrict__ qb,
                                                   const unsigned short* __restrict__ kb,
                                                   const unsigned short* __restrict__ vtb,
                                                   unsigned short* __restrict__ ao) {
    __shared__ __align__(16) unsigned short Ks[32][72];   // [key][hd]  (+8 pad)
    __shared__ __align__(16) unsigned short Vs[64][40];   // [hd][key]  (+8 pad)
    __shared__ __align__(16) unsigned short Ps[4][16][40];// per-wave [q][key]
    const int tid = threadIdx.x;
    const int lane = tid & 63, wid = tid >> 6;
    const int lr = lane & 15, lg = lane >> 4;
    const int blk = blockIdx.x;
    const int qc = blk & 63, h = (blk >> 6) & 15, b = blk >> 10;
    const int q0 = qc * 64;
    const unsigned short* Qh = qb + (size_t)(b * NH + h) * SEQ * HDIM;
    const unsigned short* Kh = kb + (size_t)(b * NH + h) * SEQ * HDIM;
    const unsigned short* Vh = vtb + (size_t)(b * NH + h) * HDIM * SEQ;
    const int qw = q0 + wid * 16;

    bf16x8 qf0 = *(const bf16x8*)(Qh + (size_t)(qw + lr) * HDIM + lg * 8);
    bf16x8 qf1 = *(const bf16x8*)(Qh + (size_t)(qw + lr) * HDIM + 32 + lg * 8);

    f32x4 oacc[4];
    float mrow[4], lsum[4];
#pragma unroll
    for (int n = 0; n < 4; ++n) {
        f32x4 z = {0.f, 0.f, 0.f, 0.f};
        oacc[n] = z;
    }
#pragma unroll
    for (int r = 0; r < 4; ++r) { mrow[r] = -1e30f; lsum[r] = 0.f; }

    int lo = q0 - 256; if (lo < 0) lo = 0;
    int hi = q0 + 320; if (hi > SEQ) hi = SEQ;

    const int krow = tid >> 3, kseg = tid & 7;   // K stage: 32 rows x 8 segs
    const int vrow = tid >> 2, vseg = tid & 3;   // V stage: 64 rows x 4 segs

    for (int kt = lo; kt < hi; kt += 32) {
        __syncthreads();
        *(us8*)&Ks[krow][kseg * 8] = *(const us8*)(Kh + (size_t)(kt + krow) * HDIM + kseg * 8);
        *(us8*)&Vs[vrow][vseg * 8] = *(const us8*)(Vh + (size_t)vrow * SEQ + kt + vseg * 8);
        __syncthreads();

        // scores: two 16-key fragments
        f32x4 sf[2];
#pragma unroll
        for (int n = 0; n < 2; ++n) {
            bf16x8 kf0 = *(const bf16x8*)&Ks[n * 16 + lr][lg * 8];
            bf16x8 kf1 = *(const bf16x8*)&Ks[n * 16 + lr][32 + lg * 8];
            f32x4 z = {0.f, 0.f, 0.f, 0.f};
            sf[n] = __builtin_amdgcn_mfma_f32_16x16x32_bf16(qf0, kf0, z, 0, 0, 0);
            sf[n] = __builtin_amdgcn_mfma_f32_16x16x32_bf16(qf1, kf1, sf[n], 0, 0, 0);
        }
        // band mask: |kpos - qpos| <= 256
#pragma unroll
        for (int r = 0; r < 4; ++r) {
            const int qpos = qw + lg * 4 + r;
#pragma unroll
            for (int n = 0; n < 2; ++n) {
                const int kpos = kt + n * 16 + lr;
                if (kpos < qpos - 256 || kpos > qpos + 256) sf[n][r] = NEGF;
            }
        }
        // online softmax
        float rmax[4], psum[4];
#pragma unroll
        for (int r = 0; r < 4; ++r) rmax[r] = fmaxf(sf[0][r], sf[1][r]);
#pragma unroll
        for (int d = 1; d < 16; d <<= 1)
#pragma unroll
            for (int r = 0; r < 4; ++r) rmax[r] = fmaxf(rmax[r], __shfl_xor(rmax[r], d, 64));
#pragma unroll
        for (int r = 0; r < 4; ++r) {
            const float mn = fmaxf(mrow[r], rmax[r]);
            const float sc = __expf(mrow[r] - mn);
            mrow[r] = mn;
            lsum[r] *= sc;
#pragma unroll
            for (int n = 0; n < 4; ++n) oacc[n][r] *= sc;
            const float p0 = __expf(sf[0][r] - mn);
            const float p1 = __expf(sf[1][r] - mn);
            Ps[wid][lg * 4 + r][lr] = f2bf(p0);
            Ps[wid][lg * 4 + r][16 + lr] = f2bf(p1);
            psum[r] = p0 + p1;
        }
#pragma unroll
        for (int d = 1; d < 16; d <<= 1)
#pragma unroll
            for (int r = 0; r < 4; ++r) psum[r] += __shfl_xor(psum[r], d, 64);
#pragma unroll
        for (int r = 0; r < 4; ++r) lsum[r] += psum[r];

        // wave-local LDS fence before re-reading P in A-operand layout
        asm volatile("s_waitcnt lgkmcnt(0)" ::: "memory");
        bf16x8 pf = *(const bf16x8*)&Ps[wid][lr][lg * 8];
#pragma unroll
        for (int n = 0; n < 4; ++n) {
            bf16x8 vf = *(const bf16x8*)&Vs[n * 16 + lr][lg * 8];
            oacc[n] = __builtin_amdgcn_mfma_f32_16x16x32_bf16(pf, vf, oacc[n], 0, 0, 0);
        }
    }

#pragma unroll
    for (int n = 0; n < 4; ++n)
#pragma unroll
        for (int r = 0; r < 4; ++r) {
            const int row = qw + lg * 4 + r;
            const float o = oacc[n][r] / lsum[r];
            ao[((size_t)b * SEQ + row) * DMODEL + h * HDIM + n * 16 + lr] = f2bf(o);
        }
}

extern "C" void kernel_launch(void* const* d_in, const int* in_sizes, int n_in,
                              void* d_out, int out_size, void* d_ws, size_t ws_size,
                              hipStream_t stream) {
    (void)in_sizes; (void)n_in; (void)out_size; (void)ws_size;
    const float* query = (const float*)d_in[0];
    const float* Wq = (const float*)d_in[1];
    const float* bq = (const float*)d_in[2];
    const float* Wk = (const float*)d_in[3];
    const float* bk = (const float*)d_in[4];
    const float* Wv = (const float*)d_in[5];
    const float* bv = (const float*)d_in[6];
    const float* Wo = (const float*)d_in[7];
    const float* bo = (const float*)d_in[8];
    float* out = (float*)d_out;

    char* ws = (char*)d_ws;
    unsigned short* xb   = (unsigned short*)ws;                       // 16MB (reused as ao)
    unsigned short* wcat = (unsigned short*)(ws + (16ull << 20));     // 6MB
    unsigned short* wot  = (unsigned short*)(ws + (22ull << 20));     // 2MB
    float*          bcat = (float*)(ws + (24ull << 20));              // 12KB
    unsigned short* qb   = (unsigned short*)(ws + (25ull << 20));     // 16MB
    unsigned short* kb   = (unsigned short*)(ws + (41ull << 20));     // 16MB
    unsigned short* vtb  = (unsigned short*)(ws + (57ull << 20));     // 16MB
    unsigned short* ao   = xb;  // xb dead after gemm1

    transpose_w<<<dim3(16, 16), dim3(64, 4), 0, stream>>>(Wq, wcat, 0.125f);
    transpose_w<<<dim3(16, 16), dim3(64, 4), 0, stream>>>(Wk, wcat + 1024 * 1024, 1.0f);
    transpose_w<<<dim3(16, 16), dim3(64, 4), 0, stream>>>(Wv, wcat + 2 * 1024 * 1024, 1.0f);
    transpose_w<<<dim3(16, 16), dim3(64, 4), 0, stream>>>(Wo, wot, 1.0f);
    build_bcat<<<12, 256, 0, stream>>>(bq, bk, bv, bcat);
    convert_x<<<8192, 256, 0, stream>>>(query, xb);

    gemm128<0><<<dim3(24, 64), 256, 0, stream>>>(xb, wcat, bcat, qb, kb, vtb, nullptr);
    attn_kernel<<<2048, 256, 0, stream>>>(qb, kb, vtb, ao);
    gemm128<1><<<dim3(8, 64), 256, 0, stream>>>(ao, wot, bo, nullptr, nullptr, nullptr, out);
}

// Round 3
// 203.567 us; speedup vs baseline: 1.2874x; 1.2874x over previous
//
#include <hip/hip_runtime.h>
#include <hip/hip_bf16.h>

#define SEQ 4096
#define BATCH 2
#define DMODEL 1024
#define NH 16
#define HDIM 64
#define NEGM (-1.0e30f)

typedef __attribute__((ext_vector_type(8))) short bf16x8;
typedef __attribute__((ext_vector_type(8))) unsigned short us8;
typedef __attribute__((ext_vector_type(4))) unsigned short us4;
typedef __attribute__((ext_vector_type(4))) float f32x4;

__device__ __forceinline__ unsigned short f2bf(float f) {
    union { float f; unsigned u; } v; v.f = f;
    unsigned u = v.u;
    return (unsigned short)((u + 0x7fffu + ((u >> 16) & 1u)) >> 16);
}

// async global->LDS, 16B per lane; LDS dest must be wave-uniform base (HW adds lane*16)
#define GL16(g, l)                                                              \
    __builtin_amdgcn_global_load_lds(                                           \
        (const __attribute__((address_space(1))) unsigned int*)(g),             \
        (__attribute__((address_space(3))) unsigned int*)(l), 16, 0, 0)

// ---------------- weight transpose + bf16 convert ----------------
__global__ __launch_bounds__(256) void transpose_w(const float* __restrict__ W,
                                                   unsigned short* __restrict__ Wt,
                                                   float scale) {
    __shared__ float tile[64][65];
    const int n0 = blockIdx.x * 64, k0 = blockIdx.y * 64;
    const int tx = threadIdx.x;
    for (int dy = threadIdx.y; dy < 64; dy += 4)
        tile[dy][tx] = W[(size_t)(k0 + dy) * DMODEL + n0 + tx];
    __syncthreads();
    for (int dy = threadIdx.y; dy < 64; dy += 4)
        Wt[(size_t)(n0 + dy) * DMODEL + k0 + tx] = f2bf(tile[tx][dy] * scale);
}

__global__ __launch_bounds__(256) void build_bcat(const float* __restrict__ bq,
                                                  const float* __restrict__ bk,
                                                  const float* __restrict__ bv,
                                                  float* __restrict__ bcat) {
    int i = blockIdx.x * 256 + threadIdx.x;
    float v;
    if (i < 1024) v = bq[i] * 0.125f;
    else if (i < 2048) v = bk[i - 1024];
    else v = bv[i - 2048];
    bcat[i] = v;
}

__global__ __launch_bounds__(256) void convert_x(const float* __restrict__ q,
                                                 unsigned short* __restrict__ xb) {
    int t = blockIdx.x * 256 + threadIdx.x;
    int d4 = (t & 255) * 4;
    int row = t >> 8;
    int b = row >> 12, s = row & (SEQ - 1);
    float4 v = *(const float4*)(q + ((size_t)s * BATCH + b) * DMODEL + d4);
    us4 o;
    o[0] = f2bf(v.x); o[1] = f2bf(v.y); o[2] = f2bf(v.z); o[3] = f2bf(v.w);
    *(us4*)(xb + (size_t)row * DMODEL + d4) = o;
}

// ---------------- 128x128 MFMA GEMM, BK=32, global_load_lds staging ----------------
template <int MODE>
__global__ __launch_bounds__(256) void gemm128(const unsigned short* __restrict__ A,
                                               const unsigned short* __restrict__ Bt,
                                               const float* __restrict__ bias,
                                               unsigned short* __restrict__ qb,
                                               unsigned short* __restrict__ kb,
                                               unsigned short* __restrict__ vtb,
                                               float* __restrict__ out) {
    __shared__ __align__(16) unsigned short As[128 * 32];
    __shared__ __align__(16) unsigned short Bs[128 * 32];
    const int tid = threadIdx.x;
    const int lane = tid & 63, wid = tid >> 6;
    const int lr = lane & 15, lg = lane >> 4;
    const int wr = wid >> 1, wc = wid & 1;
    const int m0 = blockIdx.y * 128, n0 = blockIdx.x * 128;
    // staging source coords: lane covers row wid*16 + lane/4, col elems (lane&3)*8
    const int srow = wid * 16 + (lane >> 2);
    const int scol = (lane & 3) * 8;

    f32x4 acc[4][4];
#pragma unroll
    for (int m = 0; m < 4; ++m)
#pragma unroll
        for (int n = 0; n < 4; ++n) {
            f32x4 z = {0.f, 0.f, 0.f, 0.f};
            acc[m][n] = z;
        }

    for (int k0 = 0; k0 < DMODEL; k0 += 32) {
        __syncthreads();
        const unsigned short* ga = A + (size_t)(m0 + srow) * DMODEL + k0 + scol;
        const unsigned short* gb = Bt + (size_t)(n0 + srow) * DMODEL + k0 + scol;
        GL16(ga, &As[(wid * 16) * 32]);
        GL16(ga + (size_t)64 * DMODEL, &As[(64 + wid * 16) * 32]);
        GL16(gb, &Bs[(wid * 16) * 32]);
        GL16(gb + (size_t)64 * DMODEL, &Bs[(64 + wid * 16) * 32]);
        __syncthreads();
        bf16x8 af[4], bfr[4];
#pragma unroll
        for (int m = 0; m < 4; ++m)
            af[m] = *(const bf16x8*)&As[(wr * 64 + m * 16 + lr) * 32 + lg * 8];
#pragma unroll
        for (int n = 0; n < 4; ++n)
            bfr[n] = *(const bf16x8*)&Bs[(wc * 64 + n * 16 + lr) * 32 + lg * 8];
#pragma unroll
        for (int m = 0; m < 4; ++m)
#pragma unroll
            for (int n = 0; n < 4; ++n)
                acc[m][n] = __builtin_amdgcn_mfma_f32_16x16x32_bf16(af[m], bfr[n], acc[m][n], 0, 0, 0);
    }

#pragma unroll
    for (int n = 0; n < 4; ++n) {
        const int col = n0 + wc * 64 + n * 16 + lr;
        const float bval = bias[col];
#pragma unroll
        for (int m = 0; m < 4; ++m) {
            const int row0 = m0 + wr * 64 + m * 16 + lg * 4;
            if (MODE == 0) {
                const int proj = col >> 10;
                const int ch = col & 1023;
                const int h = ch >> 6, hd = ch & 63;
                if (proj == 2) {
                    const int b = row0 >> 12, s = row0 & (SEQ - 1);
                    us4 o;
#pragma unroll
                    for (int r = 0; r < 4; ++r) o[r] = f2bf(acc[m][n][r] + bval);
                    *(us4*)(vtb + ((size_t)(b * NH + h) * HDIM + hd) * SEQ + s) = o;
                } else {
                    unsigned short* dst = (proj == 0) ? qb : kb;
#pragma unroll
                    for (int r = 0; r < 4; ++r) {
                        const int row = row0 + r;
                        const int b = row >> 12, s = row & (SEQ - 1);
                        dst[((size_t)(b * NH + h) * SEQ + s) * HDIM + hd] = f2bf(acc[m][n][r] + bval);
                    }
                }
            } else {
#pragma unroll
                for (int r = 0; r < 4; ++r) {
                    const int row = row0 + r;
                    const int b = row >> 12, s = row & (SEQ - 1);
                    out[((size_t)s * BATCH + b) * DMODEL + col] = acc[m][n][r] + bval;
                }
            }
        }
    }
}

// ---------------- banded flash attention, KVBLK=64, fixed-max softmax ----------------
__global__ __launch_bounds__(256) void attn_kernel(const unsigned short* __restrict__ qb,
                                                   const unsigned short* __restrict__ kb,
                                                   const unsigned short* __restrict__ vtb,
                                                   unsigned short* __restrict__ ao) {
    __shared__ __align__(16) unsigned short Ks[64][72];    // [key][hd]   (+8 pad)
    __shared__ __align__(16) unsigned short Vs[64][72];    // [hd][key]   (+8 pad)
    __shared__ __align__(16) unsigned short Ps[4][16][72]; // per-wave [q][key] (+8 pad)
    const int tid = threadIdx.x;
    const int lane = tid & 63, wid = tid >> 6;
    const int lr = lane & 15, lg = lane >> 4;
    const int blk = blockIdx.x;
    const int qc = blk & 63, h = (blk >> 6) & 15, b = blk >> 10;
    const int q0 = qc * 64;
    const unsigned short* Qh = qb + (size_t)(b * NH + h) * SEQ * HDIM;
    const unsigned short* Kh = kb + (size_t)(b * NH + h) * SEQ * HDIM;
    const unsigned short* Vh = vtb + (size_t)(b * NH + h) * HDIM * SEQ;
    const int qw = q0 + wid * 16;

    bf16x8 qf0 = *(const bf16x8*)(Qh + (size_t)(qw + lr) * HDIM + lg * 8);
    bf16x8 qf1 = *(const bf16x8*)(Qh + (size_t)(qw + lr) * HDIM + 32 + lg * 8);

    f32x4 oacc[4];
    float lsum[4];
#pragma unroll
    for (int n = 0; n < 4; ++n) {
        f32x4 z = {0.f, 0.f, 0.f, 0.f};
        oacc[n] = z;
    }
#pragma unroll
    for (int r = 0; r < 4; ++r) lsum[r] = 0.f;

    int lo = q0 - 256; if (lo < 0) lo = 0;
    int hi = q0 + 320; if (hi > SEQ) hi = SEQ;

    const int srow = tid >> 2, sseg = (tid & 3) * 8;  // 64 rows x 4 x 16B (x2 halves)

    for (int kt = lo; kt < hi; kt += 64) {
        __syncthreads();
        // full 64x64 coverage: two 16B chunks per thread per buffer
        *(us8*)&Ks[srow][sseg]      = *(const us8*)(Kh + (size_t)(kt + srow) * HDIM + sseg);
        *(us8*)&Ks[srow][sseg + 32] = *(const us8*)(Kh + (size_t)(kt + srow) * HDIM + sseg + 32);
        *(us8*)&Vs[srow][sseg]      = *(const us8*)(Vh + (size_t)srow * SEQ + kt + sseg);
        *(us8*)&Vs[srow][sseg + 32] = *(const us8*)(Vh + (size_t)srow * SEQ + kt + sseg + 32);
        __syncthreads();

        // scores: 4 x 16-key fragments, K=64 (2 slices)
        f32x4 sf[4];
#pragma unroll
        for (int n = 0; n < 4; ++n) {
            bf16x8 kf0 = *(const bf16x8*)&Ks[n * 16 + lr][lg * 8];
            bf16x8 kf1 = *(const bf16x8*)&Ks[n * 16 + lr][32 + lg * 8];
            f32x4 z = {0.f, 0.f, 0.f, 0.f};
            sf[n] = __builtin_amdgcn_mfma_f32_16x16x32_bf16(qf0, kf0, z, 0, 0, 0);
            sf[n] = __builtin_amdgcn_mfma_f32_16x16x32_bf16(qf1, kf1, sf[n], 0, 0, 0);
        }
        // band mask (skip when tile fully in-band for this wave's 16 rows)
        const bool full = (kt >= qw - 241) && (kt + 63 <= qw + 256);
        if (!full) {
#pragma unroll
            for (int r = 0; r < 4; ++r) {
                const int qpos = qw + lg * 4 + r;
#pragma unroll
                for (int n = 0; n < 4; ++n) {
                    const int kpos = kt + n * 16 + lr;
                    if (kpos < qpos - 256 || kpos > qpos + 256) sf[n][r] = NEGM;
                }
            }
        }
        // fixed-max softmax: p = exp(s), per-lane partial sums (reduced at end)
#pragma unroll
        for (int n = 0; n < 4; ++n)
#pragma unroll
            for (int r = 0; r < 4; ++r) {
                const float p = __expf(sf[n][r]);
                lsum[r] += p;
                Ps[wid][lg * 4 + r][n * 16 + lr] = f2bf(p);
            }

        // wave-local LDS fence before re-reading P in A-operand layout
        asm volatile("s_waitcnt lgkmcnt(0)" ::: "memory");
#pragma unroll
        for (int ks = 0; ks < 2; ++ks) {
            bf16x8 pf = *(const bf16x8*)&Ps[wid][lr][ks * 32 + lg * 8];
#pragma unroll
            for (int n = 0; n < 4; ++n) {
                bf16x8 vf = *(const bf16x8*)&Vs[n * 16 + lr][ks * 32 + lg * 8];
                oacc[n] = __builtin_amdgcn_mfma_f32_16x16x32_bf16(pf, vf, oacc[n], 0, 0, 0);
            }
        }
    }

    // reduce lsum across the 16 lr-lanes of each lg group
#pragma unroll
    for (int d = 1; d < 16; d <<= 1)
#pragma unroll
        for (int r = 0; r < 4; ++r) lsum[r] += __shfl_xor(lsum[r], d, 64);

#pragma unroll
    for (int n = 0; n < 4; ++n)
#pragma unroll
        for (int r = 0; r < 4; ++r) {
            const int row = qw + lg * 4 + r;
            const float o = oacc[n][r] / lsum[r];
            ao[((size_t)b * SEQ + row) * DMODEL + h * HDIM + n * 16 + lr] = f2bf(o);
        }
}

extern "C" void kernel_launch(void* const* d_in, const int* in_sizes, int n_in,
                              void* d_out, int out_size, void* d_ws, size_t ws_size,
                              hipStream_t stream) {
    (void)in_sizes; (void)n_in; (void)out_size; (void)ws_size;
    const float* query = (const float*)d_in[0];
    const float* Wq = (const float*)d_in[1];
    const float* bq = (const float*)d_in[2];
    const float* Wk = (const float*)d_in[3];
    const float* bk = (const float*)d_in[4];
    const float* Wv = (const float*)d_in[5];
    const float* bv = (const float*)d_in[6];
    const float* Wo = (const float*)d_in[7];
    const float* bo = (const float*)d_in[8];
    float* out = (float*)d_out;

    char* ws = (char*)d_ws;
    unsigned short* xb   = (unsigned short*)ws;                       // 16MB (reused as ao)
    unsigned short* wcat = (unsigned short*)(ws + (16ull << 20));     // 6MB
    unsigned short* wot  = (unsigned short*)(ws + (22ull << 20));     // 2MB
    float*          bcat = (float*)(ws + (24ull << 20));              // 12KB
    unsigned short* qb   = (unsigned short*)(ws + (25ull << 20));     // 16MB
    unsigned short* kb   = (unsigned short*)(ws + (41ull << 20));     // 16MB
    unsigned short* vtb  = (unsigned short*)(ws + (57ull << 20));     // 16MB
    unsigned short* ao   = xb;

    transpose_w<<<dim3(16, 16), dim3(64, 4), 0, stream>>>(Wq, wcat, 0.125f);
    transpose_w<<<dim3(16, 16), dim3(64, 4), 0, stream>>>(Wk, wcat + 1024 * 1024, 1.0f);
    transpose_w<<<dim3(16, 16), dim3(64, 4), 0, stream>>>(Wv, wcat + 2 * 1024 * 1024, 1.0f);
    transpose_w<<<dim3(16, 16), dim3(64, 4), 0, stream>>>(Wo, wot, 1.0f);
    build_bcat<<<12, 256, 0, stream>>>(bq, bk, bv, bcat);
    convert_x<<<8192, 256, 0, stream>>>(query, xb);

    gemm128<0><<<dim3(24, 64), 256, 0, stream>>>(xb, wcat, bcat, qb, kb, vtb, nullptr);
    attn_kernel<<<2048, 256, 0, stream>>>(qb, kb, vtb, ao);
    gemm128<1><<<dim3(8, 64), 256, 0, stream>>>(ao, wot, bo, nullptr, nullptr, nullptr, out);
}

// Round 5
// 180.119 us; speedup vs baseline: 1.4550x; 1.1302x over previous
//
#include <hip/hip_runtime.h>
#include <hip/hip_bf16.h>

#define SEQ 4096
#define BATCH 2
#define DMODEL 1024
#define NH 16
#define HDIM 64
#define NEGM (-1.0e30f)
#define NT 16  // DMODEL / BK(=64)

typedef __attribute__((ext_vector_type(8))) short bf16x8;
typedef __attribute__((ext_vector_type(8))) unsigned short us8;
typedef __attribute__((ext_vector_type(4))) unsigned short us4;
typedef __attribute__((ext_vector_type(4))) float f32x4;

__device__ __forceinline__ unsigned short f2bf(float f) {
    union { float f; unsigned u; } v; v.f = f;
    unsigned u = v.u;
    return (unsigned short)((u + 0x7fffu + ((u >> 16) & 1u)) >> 16);
}

// async global->LDS, 16B per lane; LDS dest wave-uniform base (HW adds lane*16)
#define GL16(g, l)                                                              \
    __builtin_amdgcn_global_load_lds(                                           \
        (const __attribute__((address_space(1))) unsigned int*)(g),             \
        (__attribute__((address_space(3))) unsigned int*)(l), 16, 0, 0)

// ---------------- weight transpose + bf16 convert ----------------
__global__ __launch_bounds__(256) void transpose_w(const float* __restrict__ W,
                                                   unsigned short* __restrict__ Wt,
                                                   float scale) {
    __shared__ float tile[64][65];
    const int n0 = blockIdx.x * 64, k0 = blockIdx.y * 64;
    const int tx = threadIdx.x;
    for (int dy = threadIdx.y; dy < 64; dy += 4)
        tile[dy][tx] = W[(size_t)(k0 + dy) * DMODEL + n0 + tx];
    __syncthreads();
    for (int dy = threadIdx.y; dy < 64; dy += 4)
        Wt[(size_t)(n0 + dy) * DMODEL + k0 + tx] = f2bf(tile[tx][dy] * scale);
}

__global__ __launch_bounds__(256) void build_bcat(const float* __restrict__ bq,
                                                  const float* __restrict__ bk,
                                                  const float* __restrict__ bv,
                                                  float* __restrict__ bcat) {
    int i = blockIdx.x * 256 + threadIdx.x;
    float v;
    if (i < 1024) v = bq[i] * 0.125f;
    else if (i < 2048) v = bk[i - 1024];
    else v = bv[i - 2048];
    bcat[i] = v;
}

__global__ __launch_bounds__(256) void convert_x(const float* __restrict__ q,
                                                 unsigned short* __restrict__ xb) {
    int t = blockIdx.x * 256 + threadIdx.x;
    int d4 = (t & 255) * 4;
    int row = t >> 8;
    int b = row >> 12, s = row & (SEQ - 1);
    float4 v = *(const float4*)(q + ((size_t)s * BATCH + b) * DMODEL + d4);
    us4 o;
    o[0] = f2bf(v.x); o[1] = f2bf(v.y); o[2] = f2bf(v.z); o[3] = f2bf(v.w);
    *(us4*)(xb + (size_t)row * DMODEL + d4) = o;
}

// ---------------- 256x128 MFMA GEMM, BK=64, double-buffer, counted vmcnt ----------------
// 8 waves (wm 0..3, wn 0..1), per-wave 64x64 output, 16x16x32 bf16 MFMA.
// LDS swizzle (T2): logical element [row][c] stored at [row][c ^ ((row&7)<<3)];
// gl_lds dest is linear, so the global SOURCE is pre-swizzled (involution).
template <int MODE, int NBX>
__global__ __launch_bounds__(512) void gemm256(const unsigned short* __restrict__ A,
                                               const unsigned short* __restrict__ Bt,
                                               const float* __restrict__ bias,
                                               unsigned short* __restrict__ qb,
                                               unsigned short* __restrict__ kb,
                                               unsigned short* __restrict__ vtb,
                                               float* __restrict__ out) {
    // 2 buffers x (A: 256x64 = 16384 us, B: 128x64 = 8192 us) = 49152 us = 96 KiB
    __shared__ __align__(16) unsigned short lds[49152];
    const int tid = threadIdx.x;
    const int lane = tid & 63, wid = tid >> 6;
    const int lr = lane & 15, lg = lane >> 4;
    const int wm = wid >> 1, wn = wid & 1;
    // T1: XCD-chunked block swizzle (gridDim.x % 8 == 0)
    const int cpx = (int)gridDim.x >> 3;
    const int orig = ((int)blockIdx.x & 7) * cpx + ((int)blockIdx.x >> 3);
    const int m0 = (orig / NBX) * 256;
    const int n0 = (orig % NBX) * 128;

    // staging source coords (per lane, pre-swizzled)
    const int srow = wid * 8 + (lane >> 3);                   // + r*64
    const int scol = ((lane & 7) ^ (lane >> 3)) << 3;         // element offset in [0,64)

    f32x4 acc[4][4];
#pragma unroll
    for (int m = 0; m < 4; ++m)
#pragma unroll
        for (int n = 0; n < 4; ++n) {
            f32x4 z = {0.f, 0.f, 0.f, 0.f};
            acc[m][n] = z;
        }

    const unsigned short* gA = A + (size_t)(m0 + srow) * DMODEL + scol;
    const unsigned short* gB = Bt + (size_t)(n0 + srow) * DMODEL + scol;

#define STAGE(kt, bsel)                                                          \
    do {                                                                         \
        const unsigned short* ga_ = gA + (kt) * 64;                              \
        unsigned short* la_ = &lds[(bsel) * 24576 + wid * 512];                  \
        _Pragma("unroll")                                                        \
        for (int r_ = 0; r_ < 4; ++r_)                                           \
            GL16(ga_ + (size_t)r_ * 64 * DMODEL, la_ + r_ * 4096);               \
        const unsigned short* gb_ = gB + (kt) * 64;                              \
        unsigned short* lb_ = &lds[(bsel) * 24576 + 16384 + wid * 512];          \
        _Pragma("unroll")                                                        \
        for (int r_ = 0; r_ < 2; ++r_)                                           \
            GL16(gb_ + (size_t)r_ * 64 * DMODEL, lb_ + r_ * 4096);               \
    } while (0)

    // prologue: stage tile 0
    STAGE(0, 0);

    const int swz = (lr & 7) << 3;
    for (int t = 0; t < NT; ++t) {
        const int bs = t & 1;
        if (t + 1 < NT) {
            STAGE(t + 1, bs ^ 1);  // issued BEFORE the counted wait; lands under compute
            asm volatile("s_waitcnt vmcnt(6)" ::: "memory");  // own tile-t loads done
        } else {
            asm volatile("s_waitcnt vmcnt(0)" ::: "memory");
        }
        __builtin_amdgcn_s_barrier();        // all waves' tile-t loads in LDS
        asm volatile("" ::: "memory");
        const unsigned short* Ab = &lds[bs * 24576];
        const unsigned short* Bb = Ab + 16384;
#pragma unroll
        for (int ks = 0; ks < 2; ++ks) {
            const int kc = (ks * 32 + lg * 8) ^ swz;
            bf16x8 af[4], bfr[4];
#pragma unroll
            for (int fm = 0; fm < 4; ++fm)
                af[fm] = *(const bf16x8*)&Ab[(wm * 64 + fm * 16 + lr) * 64 + kc];
#pragma unroll
            for (int fn = 0; fn < 4; ++fn)
                bfr[fn] = *(const bf16x8*)&Bb[(wn * 64 + fn * 16 + lr) * 64 + kc];
            __builtin_amdgcn_s_setprio(1);
#pragma unroll
            for (int fm = 0; fm < 4; ++fm)
#pragma unroll
                for (int fn = 0; fn < 4; ++fn)
                    acc[fm][fn] = __builtin_amdgcn_mfma_f32_16x16x32_bf16(af[fm], bfr[fn], acc[fm][fn], 0, 0, 0);
            __builtin_amdgcn_s_setprio(0);
        }
        asm volatile("" ::: "memory");
        __builtin_amdgcn_s_barrier();        // all reads of buf[bs] done before overwrite
        asm volatile("" ::: "memory");
    }
#undef STAGE

    // epilogue
#pragma unroll
    for (int fn = 0; fn < 4; ++fn) {
        const int col = n0 + wn * 64 + fn * 16 + lr;
        const float bval = bias[col];
#pragma unroll
        for (int fm = 0; fm < 4; ++fm) {
            const int row0 = m0 + wm * 64 + fm * 16 + lg * 4;
            if (MODE == 0) {
                const int proj = col >> 10;
                const int ch = col & 1023;
                const int h = ch >> 6, hd = ch & 63;
                if (proj == 2) {
                    const int b = row0 >> 12, s = row0 & (SEQ - 1);
                    us4 o;
#pragma unroll
                    for (int r = 0; r < 4; ++r) o[r] = f2bf(acc[fm][fn][r] + bval);
                    *(us4*)(vtb + ((size_t)(b * NH + h) * HDIM + hd) * SEQ + s) = o;
                } else {
                    unsigned short* dst = (proj == 0) ? qb : kb;
#pragma unroll
                    for (int r = 0; r < 4; ++r) {
                        const int row = row0 + r;
                        const int b = row >> 12, s = row & (SEQ - 1);
                        dst[((size_t)(b * NH + h) * SEQ + s) * HDIM + hd] = f2bf(acc[fm][fn][r] + bval);
                    }
                }
            } else {
#pragma unroll
                for (int r = 0; r < 4; ++r) {
                    const int row = row0 + r;
                    const int b = row >> 12, s = row & (SEQ - 1);
                    out[((size_t)s * BATCH + b) * DMODEL + col] = acc[fm][fn][r] + bval;
                }
            }
        }
    }
}

// ---------------- banded flash attention, KVBLK=64, fixed-max softmax ----------------
__global__ __launch_bounds__(256) void attn_kernel(const unsigned short* __restrict__ qb,
                                                   const unsigned short* __restrict__ kb,
                                                   const unsigned short* __restrict__ vtb,
                                                   unsigned short* __restrict__ ao) {
    __shared__ __align__(16) unsigned short Ks[64][72];    // [key][hd]   (+8 pad)
    __shared__ __align__(16) unsigned short Vs[64][72];    // [hd][key]   (+8 pad)
    __shared__ __align__(16) unsigned short Ps[4][16][72]; // per-wave [q][key] (+8 pad)
    const int tid = threadIdx.x;
    const int lane = tid & 63, wid = tid >> 6;
    const int lr = lane & 15, lg = lane >> 4;
    // T1: XCD-chunked swizzle; consecutive logical blocks share K/V windows
    const int blk = ((int)blockIdx.x & 7) * 256 + ((int)blockIdx.x >> 3);
    const int qc = blk & 63, h = (blk >> 6) & 15, b = blk >> 10;
    const int q0 = qc * 64;
    const unsigned short* Qh = qb + (size_t)(b * NH + h) * SEQ * HDIM;
    const unsigned short* Kh = kb + (size_t)(b * NH + h) * SEQ * HDIM;
    const unsigned short* Vh = vtb + (size_t)(b * NH + h) * HDIM * SEQ;
    const int qw = q0 + wid * 16;

    bf16x8 qf0 = *(const bf16x8*)(Qh + (size_t)(qw + lr) * HDIM + lg * 8);
    bf16x8 qf1 = *(const bf16x8*)(Qh + (size_t)(qw + lr) * HDIM + 32 + lg * 8);

    f32x4 oacc[4];
    float lsum[4];
#pragma unroll
    for (int n = 0; n < 4; ++n) {
        f32x4 z = {0.f, 0.f, 0.f, 0.f};
        oacc[n] = z;
    }
#pragma unroll
    for (int r = 0; r < 4; ++r) lsum[r] = 0.f;

    int lo = q0 - 256; if (lo < 0) lo = 0;
    int hi = q0 + 320; if (hi > SEQ) hi = SEQ;

    const int srow = tid >> 2, sseg = (tid & 3) * 8;  // 64 rows x 4 x 16B (x2 halves)

    for (int kt = lo; kt < hi; kt += 64) {
        __syncthreads();
        *(us8*)&Ks[srow][sseg]      = *(const us8*)(Kh + (size_t)(kt + srow) * HDIM + sseg);
        *(us8*)&Ks[srow][sseg + 32] = *(const us8*)(Kh + (size_t)(kt + srow) * HDIM + sseg + 32);
        *(us8*)&Vs[srow][sseg]      = *(const us8*)(Vh + (size_t)srow * SEQ + kt + sseg);
        *(us8*)&Vs[srow][sseg + 32] = *(const us8*)(Vh + (size_t)srow * SEQ + kt + sseg + 32);
        __syncthreads();

        // scores: 4 x 16-key fragments, K=64 (2 slices)
        f32x4 sf[4];
        __builtin_amdgcn_s_setprio(1);
#pragma unroll
        for (int n = 0; n < 4; ++n) {
            bf16x8 kf0 = *(const bf16x8*)&Ks[n * 16 + lr][lg * 8];
            bf16x8 kf1 = *(const bf16x8*)&Ks[n * 16 + lr][32 + lg * 8];
            f32x4 z = {0.f, 0.f, 0.f, 0.f};
            sf[n] = __builtin_amdgcn_mfma_f32_16x16x32_bf16(qf0, kf0, z, 0, 0, 0);
            sf[n] = __builtin_amdgcn_mfma_f32_16x16x32_bf16(qf1, kf1, sf[n], 0, 0, 0);
        }
        __builtin_amdgcn_s_setprio(0);
        // band mask (skip when tile fully in-band for this wave's 16 rows)
        const bool full = (kt >= qw - 241) && (kt + 63 <= qw + 256);
        if (!full) {
#pragma unroll
            for (int r = 0; r < 4; ++r) {
                const int qpos = qw + lg * 4 + r;
#pragma unroll
                for (int n = 0; n < 4; ++n) {
                    const int kpos = kt + n * 16 + lr;
                    if (kpos < qpos - 256 || kpos > qpos + 256) sf[n][r] = NEGM;
                }
            }
        }
        // fixed-max softmax: p = exp(s), per-lane partial sums (reduced at end)
#pragma unroll
        for (int n = 0; n < 4; ++n)
#pragma unroll
            for (int r = 0; r < 4; ++r) {
                const float p = __expf(sf[n][r]);
                lsum[r] += p;
                Ps[wid][lg * 4 + r][n * 16 + lr] = f2bf(p);
            }

        // wave-local LDS fence before re-reading P in A-operand layout
        asm volatile("s_waitcnt lgkmcnt(0)" ::: "memory");
        __builtin_amdgcn_s_setprio(1);
#pragma unroll
        for (int ks = 0; ks < 2; ++ks) {
            bf16x8 pf = *(const bf16x8*)&Ps[wid][lr][ks * 32 + lg * 8];
#pragma unroll
            for (int n = 0; n < 4; ++n) {
                bf16x8 vf = *(const bf16x8*)&Vs[n * 16 + lr][ks * 32 + lg * 8];
                oacc[n] = __builtin_amdgcn_mfma_f32_16x16x32_bf16(pf, vf, oacc[n], 0, 0, 0);
            }
        }
        __builtin_amdgcn_s_setprio(0);
    }

    // reduce lsum across the 16 lr-lanes of each lg group
#pragma unroll
    for (int d = 1; d < 16; d <<= 1)
#pragma unroll
        for (int r = 0; r < 4; ++r) lsum[r] += __shfl_xor(lsum[r], d, 64);

#pragma unroll
    for (int n = 0; n < 4; ++n)
#pragma unroll
        for (int r = 0; r < 4; ++r) {
            const int row = qw + lg * 4 + r;
            const float o = oacc[n][r] / lsum[r];
            ao[((size_t)b * SEQ + row) * DMODEL + h * HDIM + n * 16 + lr] = f2bf(o);
        }
}

extern "C" void kernel_launch(void* const* d_in, const int* in_sizes, int n_in,
                              void* d_out, int out_size, void* d_ws, size_t ws_size,
                              hipStream_t stream) {
    (void)in_sizes; (void)n_in; (void)out_size; (void)ws_size;
    const float* query = (const float*)d_in[0];
    const float* Wq = (const float*)d_in[1];
    const float* bq = (const float*)d_in[2];
    const float* Wk = (const float*)d_in[3];
    const float* bk = (const float*)d_in[4];
    const float* Wv = (const float*)d_in[5];
    const float* bv = (const float*)d_in[6];
    const float* Wo = (const float*)d_in[7];
    const float* bo = (const float*)d_in[8];
    float* out = (float*)d_out;

    char* ws = (char*)d_ws;
    unsigned short* xb   = (unsigned short*)ws;                       // 16MB (reused as ao)
    unsigned short* wcat = (unsigned short*)(ws + (16ull << 20));     // 6MB
    unsigned short* wot  = (unsigned short*)(ws + (22ull << 20));     // 2MB
    float*          bcat = (float*)(ws + (24ull << 20));              // 12KB
    unsigned short* qb   = (unsigned short*)(ws + (25ull << 20));     // 16MB
    unsigned short* kb   = (unsigned short*)(ws + (41ull << 20));     // 16MB
    unsigned short* vtb  = (unsigned short*)(ws + (57ull << 20));     // 16MB
    unsigned short* ao   = xb;

    transpose_w<<<dim3(16, 16), dim3(64, 4), 0, stream>>>(Wq, wcat, 0.125f);
    transpose_w<<<dim3(16, 16), dim3(64, 4), 0, stream>>>(Wk, wcat + 1024 * 1024, 1.0f);
    transpose_w<<<dim3(16, 16), dim3(64, 4), 0, stream>>>(Wv, wcat + 2 * 1024 * 1024, 1.0f);
    transpose_w<<<dim3(16, 16), dim3(64, 4), 0, stream>>>(Wo, wot, 1.0f);
    build_bcat<<<12, 256, 0, stream>>>(bq, bk, bv, bcat);
    convert_x<<<8192, 256, 0, stream>>>(query, xb);

    gemm256<0, 24><<<768, 512, 0, stream>>>(xb, wcat, bcat, qb, kb, vtb, nullptr);
    attn_kernel<<<2048, 256, 0, stream>>>(qb, kb, vtb, ao);
    gemm256<1, 8><<<256, 512, 0, stream>>>(ao, wot, bo, nullptr, nullptr, nullptr, out);
}

// Round 6
// 177.882 us; speedup vs baseline: 1.4733x; 1.0126x over previous
//
#include <hip/hip_runtime.h>
#include <hip/hip_bf16.h>

#define SEQ 4096
#define BATCH 2
#define DMODEL 1024
#define NH 16
#define HDIM 64
#define NEGM (-1.0e30f)
#define NT 16  // DMODEL / BK(=64)

typedef __attribute__((ext_vector_type(8))) short bf16x8;
typedef __attribute__((ext_vector_type(8))) unsigned short us8;
typedef __attribute__((ext_vector_type(4))) unsigned short us4;
typedef __attribute__((ext_vector_type(4))) float f32x4;

__device__ __forceinline__ unsigned short f2bf(float f) {
    union { float f; unsigned u; } v; v.f = f;
    unsigned u = v.u;
    return (unsigned short)((u + 0x7fffu + ((u >> 16) & 1u)) >> 16);
}

// async global->LDS, 16B per lane; LDS dest wave-uniform base (HW adds lane*16)
#define GL16(g, l)                                                              \
    __builtin_amdgcn_global_load_lds(                                           \
        (const __attribute__((address_space(1))) unsigned int*)(g),             \
        (__attribute__((address_space(3))) unsigned int*)(l), 16, 0, 0)

// ---------------- weight transpose + bf16 convert ----------------
__global__ __launch_bounds__(256) void transpose_w(const float* __restrict__ W,
                                                   unsigned short* __restrict__ Wt,
                                                   float scale) {
    __shared__ float tile[64][65];
    const int n0 = blockIdx.x * 64, k0 = blockIdx.y * 64;
    const int tx = threadIdx.x;
    for (int dy = threadIdx.y; dy < 64; dy += 4)
        tile[dy][tx] = W[(size_t)(k0 + dy) * DMODEL + n0 + tx];
    __syncthreads();
    for (int dy = threadIdx.y; dy < 64; dy += 4)
        Wt[(size_t)(n0 + dy) * DMODEL + k0 + tx] = f2bf(tile[tx][dy] * scale);
}

__global__ __launch_bounds__(256) void build_bcat(const float* __restrict__ bq,
                                                  const float* __restrict__ bk,
                                                  const float* __restrict__ bv,
                                                  float* __restrict__ bcat) {
    int i = blockIdx.x * 256 + threadIdx.x;
    float v;
    if (i < 1024) v = bq[i] * 0.125f;
    else if (i < 2048) v = bk[i - 1024];
    else v = bv[i - 2048];
    bcat[i] = v;
}

__global__ __launch_bounds__(256) void convert_x(const float* __restrict__ q,
                                                 unsigned short* __restrict__ xb) {
    int t = blockIdx.x * 256 + threadIdx.x;
    int d4 = (t & 255) * 4;
    int row = t >> 8;
    int b = row >> 12, s = row & (SEQ - 1);
    float4 v = *(const float4*)(q + ((size_t)s * BATCH + b) * DMODEL + d4);
    us4 o;
    o[0] = f2bf(v.x); o[1] = f2bf(v.y); o[2] = f2bf(v.z); o[3] = f2bf(v.w);
    *(us4*)(xb + (size_t)row * DMODEL + d4) = o;
}

// ---------------- 256x128 MFMA GEMM, BK=64, double-buffer, counted vmcnt ----------------
// 8 waves (wm 0..3, wn 0..1), per-wave 64x64 output, 16x16x32 bf16 MFMA.
// LDS swizzle (T2): logical element [row][c] stored at [row][c ^ ((row&7)<<3)];
// gl_lds dest is linear, so the global SOURCE is pre-swizzled (involution).
template <int MODE, int NBX>
__global__ __launch_bounds__(512) void gemm256(const unsigned short* __restrict__ A,
                                               const unsigned short* __restrict__ Bt,
                                               const float* __restrict__ bias,
                                               unsigned short* __restrict__ qb,
                                               unsigned short* __restrict__ kb,
                                               unsigned short* __restrict__ vtb,
                                               float* __restrict__ out) {
    // 2 buffers x (A: 256x64 = 16384 us, B: 128x64 = 8192 us) = 49152 us = 96 KiB
    __shared__ __align__(16) unsigned short lds[49152];
    const int tid = threadIdx.x;
    const int lane = tid & 63, wid = tid >> 6;
    const int lr = lane & 15, lg = lane >> 4;
    const int wm = wid >> 1, wn = wid & 1;
    // T1: XCD-chunked block swizzle (gridDim.x % 8 == 0)
    const int cpx = (int)gridDim.x >> 3;
    const int orig = ((int)blockIdx.x & 7) * cpx + ((int)blockIdx.x >> 3);
    const int m0 = (orig / NBX) * 256;
    const int n0 = (orig % NBX) * 128;

    // staging source coords (per lane, pre-swizzled)
    const int srow = wid * 8 + (lane >> 3);                   // + r*64
    const int scol = ((lane & 7) ^ (lane >> 3)) << 3;         // element offset in [0,64)

    f32x4 acc[4][4];
#pragma unroll
    for (int m = 0; m < 4; ++m)
#pragma unroll
        for (int n = 0; n < 4; ++n) {
            f32x4 z = {0.f, 0.f, 0.f, 0.f};
            acc[m][n] = z;
        }

    const unsigned short* gA = A + (size_t)(m0 + srow) * DMODEL + scol;
    const unsigned short* gB = Bt + (size_t)(n0 + srow) * DMODEL + scol;

#define STAGE(kt, bsel)                                                          \
    do {                                                                         \
        const unsigned short* ga_ = gA + (kt) * 64;                              \
        unsigned short* la_ = &lds[(bsel) * 24576 + wid * 512];                  \
        _Pragma("unroll")                                                        \
        for (int r_ = 0; r_ < 4; ++r_)                                           \
            GL16(ga_ + (size_t)r_ * 64 * DMODEL, la_ + r_ * 4096);               \
        const unsigned short* gb_ = gB + (kt) * 64;                              \
        unsigned short* lb_ = &lds[(bsel) * 24576 + 16384 + wid * 512];          \
        _Pragma("unroll")                                                        \
        for (int r_ = 0; r_ < 2; ++r_)                                           \
            GL16(gb_ + (size_t)r_ * 64 * DMODEL, lb_ + r_ * 4096);               \
    } while (0)

    // prologue: stage tile 0
    STAGE(0, 0);

    const int swz = (lr & 7) << 3;
    for (int t = 0; t < NT; ++t) {
        const int bs = t & 1;
        if (t + 1 < NT) {
            STAGE(t + 1, bs ^ 1);  // issued BEFORE the counted wait; lands under compute
            asm volatile("s_waitcnt vmcnt(6)" ::: "memory");  // own tile-t loads done
        } else {
            asm volatile("s_waitcnt vmcnt(0)" ::: "memory");
        }
        __builtin_amdgcn_s_barrier();        // all waves' tile-t loads in LDS
        asm volatile("" ::: "memory");
        const unsigned short* Ab = &lds[bs * 24576];
        const unsigned short* Bb = Ab + 16384;
#pragma unroll
        for (int ks = 0; ks < 2; ++ks) {
            const int kc = (ks * 32 + lg * 8) ^ swz;
            bf16x8 af[4], bfr[4];
#pragma unroll
            for (int fm = 0; fm < 4; ++fm)
                af[fm] = *(const bf16x8*)&Ab[(wm * 64 + fm * 16 + lr) * 64 + kc];
#pragma unroll
            for (int fn = 0; fn < 4; ++fn)
                bfr[fn] = *(const bf16x8*)&Bb[(wn * 64 + fn * 16 + lr) * 64 + kc];
            __builtin_amdgcn_s_setprio(1);
#pragma unroll
            for (int fm = 0; fm < 4; ++fm)
#pragma unroll
                for (int fn = 0; fn < 4; ++fn)
                    acc[fm][fn] = __builtin_amdgcn_mfma_f32_16x16x32_bf16(af[fm], bfr[fn], acc[fm][fn], 0, 0, 0);
            __builtin_amdgcn_s_setprio(0);
        }
        asm volatile("" ::: "memory");
        __builtin_amdgcn_s_barrier();        // all reads of buf[bs] done before overwrite
        asm volatile("" ::: "memory");
    }
#undef STAGE

    // epilogue
#pragma unroll
    for (int fn = 0; fn < 4; ++fn) {
        const int col = n0 + wn * 64 + fn * 16 + lr;
        const float bval = bias[col];
#pragma unroll
        for (int fm = 0; fm < 4; ++fm) {
            const int row0 = m0 + wm * 64 + fm * 16 + lg * 4;
            if (MODE == 0) {
                const int proj = col >> 10;
                const int ch = col & 1023;
                const int h = ch >> 6, hd = ch & 63;
                if (proj == 2) {
                    const int b = row0 >> 12, s = row0 & (SEQ - 1);
                    us4 o;
#pragma unroll
                    for (int r = 0; r < 4; ++r) o[r] = f2bf(acc[fm][fn][r] + bval);
                    *(us4*)(vtb + ((size_t)(b * NH + h) * HDIM + hd) * SEQ + s) = o;
                } else {
                    unsigned short* dst = (proj == 0) ? qb : kb;
#pragma unroll
                    for (int r = 0; r < 4; ++r) {
                        const int row = row0 + r;
                        const int b = row >> 12, s = row & (SEQ - 1);
                        dst[((size_t)(b * NH + h) * SEQ + s) * HDIM + hd] = f2bf(acc[fm][fn][r] + bval);
                    }
                }
            } else {
#pragma unroll
                for (int r = 0; r < 4; ++r) {
                    const int row = row0 + r;
                    const int b = row >> 12, s = row & (SEQ - 1);
                    out[((size_t)s * BATCH + b) * DMODEL + col] = acc[fm][fn][r] + bval;
                }
            }
        }
    }
}

// ---------------- banded flash attention ----------------
// QBLK=128 (8 waves x 16 q-rows), KVBLK=64, fixed-max softmax, K/V reg-prefetch (T14).
__global__ __launch_bounds__(512) void attn_kernel(const unsigned short* __restrict__ qb,
                                                   const unsigned short* __restrict__ kb,
                                                   const unsigned short* __restrict__ vtb,
                                                   unsigned short* __restrict__ ao) {
    __shared__ __align__(16) unsigned short Ks[64][72];    // [key][hd]   (+8 pad)
    __shared__ __align__(16) unsigned short Vs[64][72];    // [hd][key]   (+8 pad)
    __shared__ __align__(16) unsigned short Ps[8][16][72]; // per-wave [q][key] (+8 pad)
    const int tid = threadIdx.x;
    const int lane = tid & 63, wid = tid >> 6;
    const int lr = lane & 15, lg = lane >> 4;
    // T1: XCD-chunked swizzle (1024 blocks); consecutive logical blocks share K/V windows
    const int blk = ((int)blockIdx.x & 7) * 128 + ((int)blockIdx.x >> 3);
    const int qc = blk & 31, h = (blk >> 5) & 15, b = blk >> 9;
    const int q0 = qc * 128;
    const unsigned short* Qh = qb + (size_t)(b * NH + h) * SEQ * HDIM;
    const unsigned short* Kh = kb + (size_t)(b * NH + h) * SEQ * HDIM;
    const unsigned short* Vh = vtb + (size_t)(b * NH + h) * HDIM * SEQ;
    const int qw = q0 + wid * 16;

    bf16x8 qf0 = *(const bf16x8*)(Qh + (size_t)(qw + lr) * HDIM + lg * 8);
    bf16x8 qf1 = *(const bf16x8*)(Qh + (size_t)(qw + lr) * HDIM + 32 + lg * 8);

    f32x4 oacc[4];
    float lsum[4];
#pragma unroll
    for (int n = 0; n < 4; ++n) {
        f32x4 z = {0.f, 0.f, 0.f, 0.f};
        oacc[n] = z;
    }
#pragma unroll
    for (int r = 0; r < 4; ++r) lsum[r] = 0.f;

    int lo = q0 - 256; if (lo < 0) lo = 0;
    int hi = q0 + 384; if (hi > SEQ) hi = SEQ;

    const int srow = tid >> 3, sseg = (tid & 3 & 7) * 0 + (tid & 7) * 8;  // 64 rows x 8 x 16B

    // prologue: prefetch first tile into regs
    us8 kpre = *(const us8*)(Kh + (size_t)(lo + srow) * HDIM + sseg);
    us8 vpre = *(const us8*)(Vh + (size_t)srow * SEQ + lo + sseg);

    for (int kt = lo; kt < hi; kt += 64) {
        __syncthreads();                       // all reads of previous tile done
        *(us8*)&Ks[srow][sseg] = kpre;
        *(us8*)&Vs[srow][sseg] = vpre;
        if (kt + 64 < hi) {                    // prefetch next tile; lands under compute
            kpre = *(const us8*)(Kh + (size_t)(kt + 64 + srow) * HDIM + sseg);
            vpre = *(const us8*)(Vh + (size_t)srow * SEQ + kt + 64 + sseg);
        }
        __builtin_amdgcn_sched_barrier(0);     // don't sink the prefetch below compute
        __syncthreads();                       // tile-t K/V visible to all waves

        // scores: 4 x 16-key fragments, K=64 (2 slices)
        f32x4 sf[4];
        __builtin_amdgcn_s_setprio(1);
#pragma unroll
        for (int n = 0; n < 4; ++n) {
            bf16x8 kf0 = *(const bf16x8*)&Ks[n * 16 + lr][lg * 8];
            bf16x8 kf1 = *(const bf16x8*)&Ks[n * 16 + lr][32 + lg * 8];
            f32x4 z = {0.f, 0.f, 0.f, 0.f};
            sf[n] = __builtin_amdgcn_mfma_f32_16x16x32_bf16(qf0, kf0, z, 0, 0, 0);
            sf[n] = __builtin_amdgcn_mfma_f32_16x16x32_bf16(qf1, kf1, sf[n], 0, 0, 0);
        }
        __builtin_amdgcn_s_setprio(0);
        // band mask (skip when tile fully in-band for this wave's 16 rows)
        const bool full = (kt >= qw - 241) && (kt + 63 <= qw + 256);
        if (!full) {
#pragma unroll
            for (int r = 0; r < 4; ++r) {
                const int qpos = qw + lg * 4 + r;
#pragma unroll
                for (int n = 0; n < 4; ++n) {
                    const int kpos = kt + n * 16 + lr;
                    if (kpos < qpos - 256 || kpos > qpos + 256) sf[n][r] = NEGM;
                }
            }
        }
        // fixed-max softmax: p = exp(s), per-lane partial sums (reduced at end)
#pragma unroll
        for (int n = 0; n < 4; ++n)
#pragma unroll
            for (int r = 0; r < 4; ++r) {
                const float p = __expf(sf[n][r]);
                lsum[r] += p;
                Ps[wid][lg * 4 + r][n * 16 + lr] = f2bf(p);
            }

        // wave-local LDS fence before re-reading P in A-operand layout
        asm volatile("s_waitcnt lgkmcnt(0)" ::: "memory");
        __builtin_amdgcn_s_setprio(1);
#pragma unroll
        for (int ks = 0; ks < 2; ++ks) {
            bf16x8 pf = *(const bf16x8*)&Ps[wid][lr][ks * 32 + lg * 8];
#pragma unroll
            for (int n = 0; n < 4; ++n) {
                bf16x8 vf = *(const bf16x8*)&Vs[n * 16 + lr][ks * 32 + lg * 8];
                oacc[n] = __builtin_amdgcn_mfma_f32_16x16x32_bf16(pf, vf, oacc[n], 0, 0, 0);
            }
        }
        __builtin_amdgcn_s_setprio(0);
    }

    // reduce lsum across the 16 lr-lanes of each lg group
#pragma unroll
    for (int d = 1; d < 16; d <<= 1)
#pragma unroll
        for (int r = 0; r < 4; ++r) lsum[r] += __shfl_xor(lsum[r], d, 64);

#pragma unroll
    for (int n = 0; n < 4; ++n)
#pragma unroll
        for (int r = 0; r < 4; ++r) {
            const int row = qw + lg * 4 + r;
            const float o = oacc[n][r] / lsum[r];
            ao[((size_t)b * SEQ + row) * DMODEL + h * HDIM + n * 16 + lr] = f2bf(o);
        }
}

extern "C" void kernel_launch(void* const* d_in, const int* in_sizes, int n_in,
                              void* d_out, int out_size, void* d_ws, size_t ws_size,
                              hipStream_t stream) {
    (void)in_sizes; (void)n_in; (void)out_size; (void)ws_size;
    const float* query = (const float*)d_in[0];
    const float* Wq = (const float*)d_in[1];
    const float* bq = (const float*)d_in[2];
    const float* Wk = (const float*)d_in[3];
    const float* bk = (const float*)d_in[4];
    const float* Wv = (const float*)d_in[5];
    const float* bv = (const float*)d_in[6];
    const float* Wo = (const float*)d_in[7];
    const float* bo = (const float*)d_in[8];
    float* out = (float*)d_out;

    char* ws = (char*)d_ws;
    unsigned short* xb   = (unsigned short*)ws;                       // 16MB (reused as ao)
    unsigned short* wcat = (unsigned short*)(ws + (16ull << 20));     // 6MB
    unsigned short* wot  = (unsigned short*)(ws + (22ull << 20));     // 2MB
    float*          bcat = (float*)(ws + (24ull << 20));              // 12KB
    unsigned short* qb   = (unsigned short*)(ws + (25ull << 20));     // 16MB
    unsigned short* kb   = (unsigned short*)(ws + (41ull << 20));     // 16MB
    unsigned short* vtb  = (unsigned short*)(ws + (57ull << 20));     // 16MB
    unsigned short* ao   = xb;

    transpose_w<<<dim3(16, 16), dim3(64, 4), 0, stream>>>(Wq, wcat, 0.125f);
    transpose_w<<<dim3(16, 16), dim3(64, 4), 0, stream>>>(Wk, wcat + 1024 * 1024, 1.0f);
    transpose_w<<<dim3(16, 16), dim3(64, 4), 0, stream>>>(Wv, wcat + 2 * 1024 * 1024, 1.0f);
    transpose_w<<<dim3(16, 16), dim3(64, 4), 0, stream>>>(Wo, wot, 1.0f);
    build_bcat<<<12, 256, 0, stream>>>(bq, bk, bv, bcat);
    convert_x<<<8192, 256, 0, stream>>>(query, xb);

    gemm256<0, 24><<<768, 512, 0, stream>>>(xb, wcat, bcat, qb, kb, vtb, nullptr);
    attn_kernel<<<1024, 512, 0, stream>>>(qb, kb, vtb, ao);
    gemm256<1, 8><<<256, 512, 0, stream>>>(ao, wot, bo, nullptr, nullptr, nullptr, out);
}

// Round 7
// 177.113 us; speedup vs baseline: 1.4797x; 1.0043x over previous
//
#include <hip/hip_runtime.h>
#include <hip/hip_bf16.h>

#define SEQ 4096
#define BATCH 2
#define DMODEL 1024
#define NH 16
#define HDIM 64
#define NEGM (-1.0e30f)
#define NT 16  // DMODEL / BK(=64)

typedef __attribute__((ext_vector_type(8))) short bf16x8;
typedef __attribute__((ext_vector_type(8))) unsigned short us8;
typedef __attribute__((ext_vector_type(4))) unsigned short us4;
typedef __attribute__((ext_vector_type(4))) float f32x4;

__device__ __forceinline__ unsigned short f2bf(float f) {
    union { float f; unsigned u; } v; v.f = f;
    unsigned u = v.u;
    return (unsigned short)((u + 0x7fffu + ((u >> 16) & 1u)) >> 16);
}

// async global->LDS, 16B per lane; LDS dest wave-uniform base (HW adds lane*16)
#define GL16(g, l)                                                              \
    __builtin_amdgcn_global_load_lds(                                           \
        (const __attribute__((address_space(1))) unsigned int*)(g),             \
        (__attribute__((address_space(3))) unsigned int*)(l), 16, 0, 0)

// ---------------- weight transpose + bf16 convert ----------------
__global__ __launch_bounds__(256) void transpose_w(const float* __restrict__ W,
                                                   unsigned short* __restrict__ Wt,
                                                   float scale) {
    __shared__ float tile[64][65];
    const int n0 = blockIdx.x * 64, k0 = blockIdx.y * 64;
    const int tx = threadIdx.x;
    for (int dy = threadIdx.y; dy < 64; dy += 4)
        tile[dy][tx] = W[(size_t)(k0 + dy) * DMODEL + n0 + tx];
    __syncthreads();
    for (int dy = threadIdx.y; dy < 64; dy += 4)
        Wt[(size_t)(n0 + dy) * DMODEL + k0 + tx] = f2bf(tile[tx][dy] * scale);
}

__global__ __launch_bounds__(256) void build_bcat(const float* __restrict__ bq,
                                                  const float* __restrict__ bk,
                                                  const float* __restrict__ bv,
                                                  float* __restrict__ bcat) {
    int i = blockIdx.x * 256 + threadIdx.x;
    float v;
    if (i < 1024) v = bq[i] * 0.125f;
    else if (i < 2048) v = bk[i - 1024];
    else v = bv[i - 2048];
    bcat[i] = v;
}

__global__ __launch_bounds__(256) void convert_x(const float* __restrict__ q,
                                                 unsigned short* __restrict__ xb) {
    int t = blockIdx.x * 256 + threadIdx.x;
    int d4 = (t & 255) * 4;
    int row = t >> 8;
    int b = row >> 12, s = row & (SEQ - 1);
    float4 v = *(const float4*)(q + ((size_t)s * BATCH + b) * DMODEL + d4);
    us4 o;
    o[0] = f2bf(v.x); o[1] = f2bf(v.y); o[2] = f2bf(v.z); o[3] = f2bf(v.w);
    *(us4*)(xb + (size_t)row * DMODEL + d4) = o;
}

// ------- 256x128 MFMA GEMM, BK=64, TRIPLE-buffer, stage-2-ahead, 2 phases/tile -------
// 8 waves (wm 0..3, wn 0..1), per-wave 64x64 output, 16x16x32 bf16 MFMA.
// T2 swizzle: logical [row][c] at [row][c ^ ((row&7)<<3)]; source pre-swizzled.
// T3/T4: per tile {P1: ds_read A+B01 | stage A(t+2); bar; lgk0; 16 MFMA; bar}
//                 {P2: ds_read B23   | stage B(t+2); bar; lgk0; 16 MFMA; vmcnt(6); bar}
// vmcnt(6) drains tile t+1 (t+2's 6 loads stay in flight) -> never 0 mid-loop.
template <int MODE, int NBX>
__global__ __launch_bounds__(512) void gemm256(const unsigned short* __restrict__ A,
                                               const unsigned short* __restrict__ Bt,
                                               const float* __restrict__ bias,
                                               unsigned short* __restrict__ qb,
                                               unsigned short* __restrict__ kb,
                                               unsigned short* __restrict__ vtb,
                                               float* __restrict__ out) {
    // 3 buffers x (A: 256x64 = 16384 us, B: 128x64 = 8192 us) = 73728 us = 144 KiB
    __shared__ __align__(16) unsigned short lds[73728];
    const int tid = threadIdx.x;
    const int lane = tid & 63, wid = tid >> 6;
    const int lr = lane & 15, lg = lane >> 4;
    const int wm = wid >> 1, wn = wid & 1;
    // T1: XCD-chunked block swizzle (gridDim.x % 8 == 0)
    const int cpx = (int)gridDim.x >> 3;
    const int orig = ((int)blockIdx.x & 7) * cpx + ((int)blockIdx.x >> 3);
    const int m0 = (orig / NBX) * 256;
    const int n0 = (orig % NBX) * 128;

    // staging source coords (per lane, pre-swizzled)
    const int srow = wid * 8 + (lane >> 3);                   // + r*64
    const int scol = ((lane & 7) ^ (lane >> 3)) << 3;         // element offset in [0,64)

    f32x4 acc[4][4];
#pragma unroll
    for (int m = 0; m < 4; ++m)
#pragma unroll
        for (int n = 0; n < 4; ++n) {
            f32x4 z = {0.f, 0.f, 0.f, 0.f};
            acc[m][n] = z;
        }

    const unsigned short* gA = A + (size_t)(m0 + srow) * DMODEL + scol;
    const unsigned short* gB = Bt + (size_t)(n0 + srow) * DMODEL + scol;

#define STAGE_A(kt, bsel)                                                        \
    do {                                                                         \
        const unsigned short* ga_ = gA + (kt) * 64;                              \
        unsigned short* la_ = &lds[(bsel) * 24576 + wid * 512];                  \
        _Pragma("unroll")                                                        \
        for (int r_ = 0; r_ < 4; ++r_)                                           \
            GL16(ga_ + (size_t)r_ * 64 * DMODEL, la_ + r_ * 4096);               \
    } while (0)
#define STAGE_B(kt, bsel)                                                        \
    do {                                                                         \
        const unsigned short* gb_ = gB + (kt) * 64;                              \
        unsigned short* lb_ = &lds[(bsel) * 24576 + 16384 + wid * 512];          \
        _Pragma("unroll")                                                        \
        for (int r_ = 0; r_ < 2; ++r_)                                           \
            GL16(gb_ + (size_t)r_ * 64 * DMODEL, lb_ + r_ * 4096);               \
    } while (0)

    // prologue: stage tiles 0 and 1, make tile 0 resident (tile 1 stays in flight)
    STAGE_A(0, 0); STAGE_B(0, 0);
    STAGE_A(1, 1); STAGE_B(1, 1);
    asm volatile("s_waitcnt vmcnt(6)" ::: "memory");
    __builtin_amdgcn_s_barrier();
    asm volatile("" ::: "memory");

    const int swz = (lr & 7) << 3;
    int bs = 0;  // buffer holding tile t  (t % 3)
    for (int t = 0; t < NT; ++t) {
        const int b2 = bs >= 1 ? bs - 1 : bs + 2;   // (t+2) % 3
        const unsigned short* Ab = &lds[bs * 24576];
        const unsigned short* Bb = Ab + 16384;

        // ---- Phase 1: A frags + B frags fn0-1; stage A(t+2) ----
        bf16x8 af[4][2], bf01[2][2];
#pragma unroll
        for (int fm = 0; fm < 4; ++fm)
#pragma unroll
            for (int ks = 0; ks < 2; ++ks)
                af[fm][ks] = *(const bf16x8*)&Ab[(wm * 64 + fm * 16 + lr) * 64 + ((ks * 32 + lg * 8) ^ swz)];
#pragma unroll
        for (int fn = 0; fn < 2; ++fn)
#pragma unroll
            for (int ks = 0; ks < 2; ++ks)
                bf01[fn][ks] = *(const bf16x8*)&Bb[(wn * 64 + fn * 16 + lr) * 64 + ((ks * 32 + lg * 8) ^ swz)];
        if (t + 2 < NT) STAGE_A(t + 2, b2);
        __builtin_amdgcn_s_barrier();
        asm volatile("s_waitcnt lgkmcnt(0)" ::: "memory");
        __builtin_amdgcn_sched_barrier(0);
        __builtin_amdgcn_s_setprio(1);
#pragma unroll
        for (int fm = 0; fm < 4; ++fm)
#pragma unroll
            for (int fn = 0; fn < 2; ++fn)
#pragma unroll
                for (int ks = 0; ks < 2; ++ks)
                    acc[fm][fn] = __builtin_amdgcn_mfma_f32_16x16x32_bf16(af[fm][ks], bf01[fn][ks], acc[fm][fn], 0, 0, 0);
        __builtin_amdgcn_s_setprio(0);
        asm volatile("" ::: "memory");
        __builtin_amdgcn_s_barrier();
        asm volatile("" ::: "memory");

        // ---- Phase 2: B frags fn2-3; stage B(t+2) ----
        bf16x8 bf23[2][2];
#pragma unroll
        for (int fn = 0; fn < 2; ++fn)
#pragma unroll
            for (int ks = 0; ks < 2; ++ks)
                bf23[fn][ks] = *(const bf16x8*)&Bb[(wn * 64 + (fn + 2) * 16 + lr) * 64 + ((ks * 32 + lg * 8) ^ swz)];
        if (t + 2 < NT) STAGE_B(t + 2, b2);
        __builtin_amdgcn_s_barrier();
        asm volatile("s_waitcnt lgkmcnt(0)" ::: "memory");
        __builtin_amdgcn_sched_barrier(0);
        __builtin_amdgcn_s_setprio(1);
#pragma unroll
        for (int fm = 0; fm < 4; ++fm)
#pragma unroll
            for (int fn = 0; fn < 2; ++fn)
#pragma unroll
                for (int ks = 0; ks < 2; ++ks)
                    acc[fm][fn + 2] = __builtin_amdgcn_mfma_f32_16x16x32_bf16(af[fm][ks], bf23[fn][ks], acc[fm][fn + 2], 0, 0, 0);
        __builtin_amdgcn_s_setprio(0);
        // drain tile t+1's loads (t+2's stay in flight); tail tiles drain fully
        if (t + 2 < NT)
            asm volatile("s_waitcnt vmcnt(6)" ::: "memory");
        else
            asm volatile("s_waitcnt vmcnt(0)" ::: "memory");
        __builtin_amdgcn_s_barrier();   // doubles as next tile's residency gate
        asm volatile("" ::: "memory");
        bs = bs < 2 ? bs + 1 : 0;
    }
#undef STAGE_A
#undef STAGE_B

    // epilogue
#pragma unroll
    for (int fn = 0; fn < 4; ++fn) {
        const int col = n0 + wn * 64 + fn * 16 + lr;
        const float bval = bias[col];
#pragma unroll
        for (int fm = 0; fm < 4; ++fm) {
            const int row0 = m0 + wm * 64 + fm * 16 + lg * 4;
            if (MODE == 0) {
                const int proj = col >> 10;
                const int ch = col & 1023;
                const int h = ch >> 6, hd = ch & 63;
                if (proj == 2) {
                    const int b = row0 >> 12, s = row0 & (SEQ - 1);
                    us4 o;
#pragma unroll
                    for (int r = 0; r < 4; ++r) o[r] = f2bf(acc[fm][fn][r] + bval);
                    *(us4*)(vtb + ((size_t)(b * NH + h) * HDIM + hd) * SEQ + s) = o;
                } else {
                    unsigned short* dst = (proj == 0) ? qb : kb;
#pragma unroll
                    for (int r = 0; r < 4; ++r) {
                        const int row = row0 + r;
                        const int b = row >> 12, s = row & (SEQ - 1);
                        dst[((size_t)(b * NH + h) * SEQ + s) * HDIM + hd] = f2bf(acc[fm][fn][r] + bval);
                    }
                }
            } else {
#pragma unroll
                for (int r = 0; r < 4; ++r) {
                    const int row = row0 + r;
                    const int b = row >> 12, s = row & (SEQ - 1);
                    out[((size_t)s * BATCH + b) * DMODEL + col] = acc[fm][fn][r] + bval;
                }
            }
        }
    }
}

// ---------------- banded flash attention ----------------
// QBLK=128 (8 waves x 16 q-rows), KVBLK=64, fixed-max softmax, K/V reg-prefetch (T14).
__global__ __launch_bounds__(512) void attn_kernel(const unsigned short* __restrict__ qb,
                                                   const unsigned short* __restrict__ kb,
                                                   const unsigned short* __restrict__ vtb,
                                                   unsigned short* __restrict__ ao) {
    __shared__ __align__(16) unsigned short Ks[64][72];    // [key][hd]   (+8 pad)
    __shared__ __align__(16) unsigned short Vs[64][72];    // [hd][key]   (+8 pad)
    __shared__ __align__(16) unsigned short Ps[8][16][72]; // per-wave [q][key] (+8 pad)
    const int tid = threadIdx.x;
    const int lane = tid & 63, wid = tid >> 6;
    const int lr = lane & 15, lg = lane >> 4;
    // T1: XCD-chunked swizzle (1024 blocks); consecutive logical blocks share K/V windows
    const int blk = ((int)blockIdx.x & 7) * 128 + ((int)blockIdx.x >> 3);
    const int qc = blk & 31, h = (blk >> 5) & 15, b = blk >> 9;
    const int q0 = qc * 128;
    const unsigned short* Qh = qb + (size_t)(b * NH + h) * SEQ * HDIM;
    const unsigned short* Kh = kb + (size_t)(b * NH + h) * SEQ * HDIM;
    const unsigned short* Vh = vtb + (size_t)(b * NH + h) * HDIM * SEQ;
    const int qw = q0 + wid * 16;

    bf16x8 qf0 = *(const bf16x8*)(Qh + (size_t)(qw + lr) * HDIM + lg * 8);
    bf16x8 qf1 = *(const bf16x8*)(Qh + (size_t)(qw + lr) * HDIM + 32 + lg * 8);

    f32x4 oacc[4];
    float lsum[4];
#pragma unroll
    for (int n = 0; n < 4; ++n) {
        f32x4 z = {0.f, 0.f, 0.f, 0.f};
        oacc[n] = z;
    }
#pragma unroll
    for (int r = 0; r < 4; ++r) lsum[r] = 0.f;

    int lo = q0 - 256; if (lo < 0) lo = 0;
    int hi = q0 + 384; if (hi > SEQ) hi = SEQ;

    const int srow = tid >> 3, sseg = (tid & 7) * 8;  // 64 rows x 8 x 16B

    // prologue: prefetch first tile into regs
    us8 kpre = *(const us8*)(Kh + (size_t)(lo + srow) * HDIM + sseg);
    us8 vpre = *(const us8*)(Vh + (size_t)srow * SEQ + lo + sseg);

    for (int kt = lo; kt < hi; kt += 64) {
        __syncthreads();                       // all reads of previous tile done
        *(us8*)&Ks[srow][sseg] = kpre;
        *(us8*)&Vs[srow][sseg] = vpre;
        if (kt + 64 < hi) {                    // prefetch next tile; lands under compute
            kpre = *(const us8*)(Kh + (size_t)(kt + 64 + srow) * HDIM + sseg);
            vpre = *(const us8*)(Vh + (size_t)srow * SEQ + kt + 64 + sseg);
        }
        __builtin_amdgcn_sched_barrier(0);     // don't sink the prefetch below compute
        __syncthreads();                       // tile-t K/V visible to all waves

        // scores: 4 x 16-key fragments, K=64 (2 slices)
        f32x4 sf[4];
        __builtin_amdgcn_s_setprio(1);
#pragma unroll
        for (int n = 0; n < 4; ++n) {
            bf16x8 kf0 = *(const bf16x8*)&Ks[n * 16 + lr][lg * 8];
            bf16x8 kf1 = *(const bf16x8*)&Ks[n * 16 + lr][32 + lg * 8];
            f32x4 z = {0.f, 0.f, 0.f, 0.f};
            sf[n] = __builtin_amdgcn_mfma_f32_16x16x32_bf16(qf0, kf0, z, 0, 0, 0);
            sf[n] = __builtin_amdgcn_mfma_f32_16x16x32_bf16(qf1, kf1, sf[n], 0, 0, 0);
        }
        __builtin_amdgcn_s_setprio(0);
        // band mask (skip when tile fully in-band for this wave's 16 rows)
        const bool full = (kt >= qw - 241) && (kt + 63 <= qw + 256);
        if (!full) {
#pragma unroll
            for (int r = 0; r < 4; ++r) {
                const int qpos = qw + lg * 4 + r;
#pragma unroll
                for (int n = 0; n < 4; ++n) {
                    const int kpos = kt + n * 16 + lr;
                    if (kpos < qpos - 256 || kpos > qpos + 256) sf[n][r] = NEGM;
                }
            }
        }
        // fixed-max softmax: p = exp(s), per-lane partial sums (reduced at end)
#pragma unroll
        for (int n = 0; n < 4; ++n)
#pragma unroll
            for (int r = 0; r < 4; ++r) {
                const float p = __expf(sf[n][r]);
                lsum[r] += p;
                Ps[wid][lg * 4 + r][n * 16 + lr] = f2bf(p);
            }

        // wave-local LDS fence before re-reading P in A-operand layout
        asm volatile("s_waitcnt lgkmcnt(0)" ::: "memory");
        __builtin_amdgcn_s_setprio(1);
#pragma unroll
        for (int ks = 0; ks < 2; ++ks) {
            bf16x8 pf = *(const bf16x8*)&Ps[wid][lr][ks * 32 + lg * 8];
#pragma unroll
            for (int n = 0; n < 4; ++n) {
                bf16x8 vf = *(const bf16x8*)&Vs[n * 16 + lr][ks * 32 + lg * 8];
                oacc[n] = __builtin_amdgcn_mfma_f32_16x16x32_bf16(pf, vf, oacc[n], 0, 0, 0);
            }
        }
        __builtin_amdgcn_s_setprio(0);
    }

    // reduce lsum across the 16 lr-lanes of each lg group
#pragma unroll
    for (int d = 1; d < 16; d <<= 1)
#pragma unroll
        for (int r = 0; r < 4; ++r) lsum[r] += __shfl_xor(lsum[r], d, 64);

#pragma unroll
    for (int n = 0; n < 4; ++n)
#pragma unroll
        for (int r = 0; r < 4; ++r) {
            const int row = qw + lg * 4 + r;
            const float o = oacc[n][r] / lsum[r];
            ao[((size_t)b * SEQ + row) * DMODEL + h * HDIM + n * 16 + lr] = f2bf(o);
        }
}

extern "C" void kernel_launch(void* const* d_in, const int* in_sizes, int n_in,
                              void* d_out, int out_size, void* d_ws, size_t ws_size,
                              hipStream_t stream) {
    (void)in_sizes; (void)n_in; (void)out_size; (void)ws_size;
    const float* query = (const float*)d_in[0];
    const float* Wq = (const float*)d_in[1];
    const float* bq = (const float*)d_in[2];
    const float* Wk = (const float*)d_in[3];
    const float* bk = (const float*)d_in[4];
    const float* Wv = (const float*)d_in[5];
    const float* bv = (const float*)d_in[6];
    const float* Wo = (const float*)d_in[7];
    const float* bo = (const float*)d_in[8];
    float* out = (float*)d_out;

    char* ws = (char*)d_ws;
    unsigned short* xb   = (unsigned short*)ws;                       // 16MB (reused as ao)
    unsigned short* wcat = (unsigned short*)(ws + (16ull << 20));     // 6MB
    unsigned short* wot  = (unsigned short*)(ws + (22ull << 20));     // 2MB
    float*          bcat = (float*)(ws + (24ull << 20));              // 12KB
    unsigned short* qb   = (unsigned short*)(ws + (25ull << 20));     // 16MB
    unsigned short* kb   = (unsigned short*)(ws + (41ull << 20));     // 16MB
    unsigned short* vtb  = (unsigned short*)(ws + (57ull << 20));     // 16MB
    unsigned short* ao   = xb;

    transpose_w<<<dim3(16, 16), dim3(64, 4), 0, stream>>>(Wq, wcat, 0.125f);
    transpose_w<<<dim3(16, 16), dim3(64, 4), 0, stream>>>(Wk, wcat + 1024 * 1024, 1.0f);
    transpose_w<<<dim3(16, 16), dim3(64, 4), 0, stream>>>(Wv, wcat + 2 * 1024 * 1024, 1.0f);
    transpose_w<<<dim3(16, 16), dim3(64, 4), 0, stream>>>(Wo, wot, 1.0f);
    build_bcat<<<12, 256, 0, stream>>>(bq, bk, bv, bcat);
    convert_x<<<8192, 256, 0, stream>>>(query, xb);

    gemm256<0, 24><<<768, 512, 0, stream>>>(xb, wcat, bcat, qb, kb, vtb, nullptr);
    attn_kernel<<<1024, 512, 0, stream>>>(qb, kb, vtb, ao);
    gemm256<1, 8><<<256, 512, 0, stream>>>(ao, wot, bo, nullptr, nullptr, nullptr, out);
}